// Round 2
// baseline (234.714 us; speedup 1.0000x reference)
//
#include <hip/hip_runtime.h>
#include <stdint.h>

#define SLEN 512
#define NT 48
#define NEG_INF_V -10000.0f
#define TAG_START 46
#define TAG_STOP 47

typedef const uint32_t __attribute__((address_space(1)))* gptr_t;
typedef uint32_t __attribute__((address_space(3)))* lptr_t;

__device__ __forceinline__ float bcast(float v, int l) {
  return __int_as_float(__builtin_amdgcn_readlane(__float_as_int(v), l));
}

__device__ __forceinline__ void gload16(const float* g, float* l) {
  __builtin_amdgcn_global_load_lds((gptr_t)(uintptr_t)g, (lptr_t)(uintptr_t)l,
                                   16, 0, 0);
}

// One wave (64 threads) per batch element. Lane j owns tag j (j<48).
__global__ __launch_bounds__(64) void crf_fwd_kernel(
    const float* __restrict__ em, const int* __restrict__ tags,
    const int* __restrict__ mask, const float* __restrict__ Tr,
    float* __restrict__ ws) {
  const int b = blockIdx.x;
  const int lane = threadIdx.x;
  __shared__ __align__(16) float lem[64 * NT];  // 12 KB: 64-step emission chunk

  // length = sum(mask row)  (mask is a prefix mask by construction)
  const int* mrow = mask + (size_t)b * SLEN;
  int lc = 0;
  for (int t = lane; t < SLEN; t += 64) lc += mrow[t];
#pragma unroll
  for (int d = 32; d >= 1; d >>= 1) lc += __shfl_xor(lc, d);
  const int len = lc;  // uniform across wave; len >= 256 by setup

  // E[i][lane] = exp(T[i][lane]); exp(-10000) underflows to exactly 0,
  // reproducing the NEG_INF barrier semantics (column START, row STOP).
  float Ec[NT];
#pragma unroll
  for (int i = 0; i < NT; ++i)
    Ec[i] = (lane < NT) ? __expf(Tr[i * NT + lane]) : 0.0f;

  // alpha0: 0 at START, NEG_INF elsewhere; idle lanes at -inf
  float alpha = (lane < NT) ? ((lane == TAG_START) ? 0.0f : NEG_INF_V)
                            : -__builtin_inff();

  const float* embase = em + (size_t)b * SLEN * NT;

  for (int c0 = 0; c0 < len; c0 += 64) {
    // Stage 64 steps (64*48*4B = 12288B) of emissions into LDS.
    // c0 <= 448 always, so reads stay inside this batch's rows.
    const float* src = embase + (size_t)c0 * NT;
#pragma unroll
    for (int k = 0; k < 12; ++k)
      gload16(src + k * 256 + lane * 4, lem + k * 256);
    asm volatile("s_waitcnt vmcnt(0)" ::: "memory");

    const int tend = (len - c0 < 64) ? (len - c0) : 64;
    for (int tt = 0; tt < tend; ++tt) {
      float e = (lane < NT) ? lem[tt * NT + lane] : 0.0f;

      // wave max of alpha (exact; idle lanes are -inf)
      float m = alpha;
#pragma unroll
      for (int d = 32; d >= 1; d >>= 1) m = fmaxf(m, __shfl_xor(m, d));

      const float pv = __expf(alpha - m);  // -inf -> 0, NEG_INF-ish -> 0

      // s_j = sum_i p_i * E[i][j]; p_i broadcast via readlane -> SGPR fma operand
      float s0 = 0.f, s1 = 0.f, s2 = 0.f, s3 = 0.f;
#pragma unroll
      for (int i = 0; i < NT; i += 4) {
        s0 = fmaf(bcast(pv, i + 0), Ec[i + 0], s0);
        s1 = fmaf(bcast(pv, i + 1), Ec[i + 1], s1);
        s2 = fmaf(bcast(pv, i + 2), Ec[i + 2], s2);
        s3 = fmaf(bcast(pv, i + 3), Ec[i + 3], s3);
      }
      const float ssum = (s0 + s1) + (s2 + s3);

      // lane>=48 or j==START column: ssum==0 -> log -> -inf (matches ref semantics)
      alpha = m + __logf(ssum) + e;
    }
  }

  // log Z = LSE_j(alpha_j + T[STOP][j])
  float term = (lane < NT) ? alpha + Tr[TAG_STOP * NT + lane] : -__builtin_inff();
  float m2 = term;
#pragma unroll
  for (int d = 32; d >= 1; d >>= 1) m2 = fmaxf(m2, __shfl_xor(m2, d));
  float ex = (lane < NT) ? __expf(term - m2) : 0.0f;
#pragma unroll
  for (int d = 32; d >= 1; d >>= 1) ex += __shfl_xor(ex, d);
  const float logZ = m2 + __logf(ex);

  // gold score: sum_t<len T[tag_t][prev_t] + em[t][tag_t], + T[STOP][last]
  const int* trow = tags + (size_t)b * SLEN;
  float g = 0.f;
  for (int t = lane; t < len; t += 64) {
    const int tag = trow[t];
    const int prev = (t == 0) ? TAG_START : trow[t - 1];
    g += Tr[tag * NT + prev] + embase[(size_t)t * NT + tag];
  }
#pragma unroll
  for (int d = 32; d >= 1; d >>= 1) g += __shfl_xor(g, d);

  if (lane == 0) {
    const int last = trow[len - 1];
    ws[b] = logZ - (g + Tr[TAG_STOP * NT + last]);
  }
}

// Deterministic tree-mean over B per-batch values (no atomics).
__global__ void crf_reduce_kernel(const float* __restrict__ ws,
                                  float* __restrict__ out, int n) {
  const int tid = threadIdx.x;
  float v = (tid < n) ? ws[tid] : 0.f;
#pragma unroll
  for (int d = 32; d >= 1; d >>= 1) v += __shfl_xor(v, d);
  __shared__ float part[16];
  if ((tid & 63) == 0) part[tid >> 6] = v;
  __syncthreads();
  if (tid == 0) {
    float s = 0.f;
    for (int i = 0; i < 16; ++i) s += part[i];
    out[0] = s / (float)n;
  }
}

extern "C" void kernel_launch(void* const* d_in, const int* in_sizes, int n_in,
                              void* d_out, int out_size, void* d_ws, size_t ws_size,
                              hipStream_t stream) {
  const float* em = (const float*)d_in[0];
  const int* tags = (const int*)d_in[1];
  const int* mask = (const int*)d_in[2];
  const float* Tr = (const float*)d_in[3];
  const int B = in_sizes[0] / (SLEN * NT);  // 1024

  float* ws = (float*)d_ws;  // B floats
  crf_fwd_kernel<<<B, 64, 0, stream>>>(em, tags, mask, Tr, ws);
  crf_reduce_kernel<<<1, 1024, 0, stream>>>(ws, (float*)d_out, B);
}

// Round 3
// 109.171 us; speedup vs baseline: 2.1500x; 2.1500x over previous
//
#include <hip/hip_runtime.h>
#include <stdint.h>
#include <math.h>

#define SLEN 512
#define NT 48
#define TAG_START 46
#define TAG_STOP 47

typedef const uint32_t __attribute__((address_space(1)))* gptr_t;
typedef uint32_t __attribute__((address_space(3)))* lptr_t;

__device__ __forceinline__ float bcast(float v, int l) {
  return __int_as_float(__builtin_amdgcn_readlane(__float_as_int(v), l));
}

__device__ __forceinline__ void gload16(const float* g, float* l) {
  __builtin_amdgcn_global_load_lds((gptr_t)(uintptr_t)g, (lptr_t)(uintptr_t)l,
                                   16, 0, 0);
}

// One wave per batch element. Lane j owns tag j (j<48).
// State kept LINEAR: q_j = exp(alpha_j - C), C = cbits*ln2 (uniform scalar).
// Step: q <- (q . E) * exp(emit_t)   -- no per-step max/log/shuffles.
__global__ __launch_bounds__(64) void crf_fwd_kernel(
    const float* __restrict__ em, const int* __restrict__ tags,
    const int* __restrict__ mask, const float* __restrict__ Tr,
    float* __restrict__ ws) {
  const int b = blockIdx.x;
  const int lane = threadIdx.x;
  __shared__ __align__(16) float lem[64 * NT + 16];  // +pad: idle-lane reads stay in-bounds

  // length = sum(mask row)  (prefix mask)
  const int* mrow = mask + (size_t)b * SLEN;
  int lc = 0;
  for (int t = lane; t < SLEN; t += 64) lc += mrow[t];
#pragma unroll
  for (int d = 32; d >= 1; d >>= 1) lc += __shfl_xor(lc, d);
  const int len = lc;

  // E[i][lane] = exp(T[i][lane]); exp(-10000) -> exactly 0 reproduces the
  // NEG_INF barriers (col START, row STOP). Ec=0 for idle lanes keeps q=0 there.
  float Ec[NT];
#pragma unroll
  for (int i = 0; i < NT; ++i)
    Ec[i] = (lane < NT) ? __expf(Tr[i * NT + lane]) : 0.0f;

  float q = (lane == TAG_START) ? 1.0f : 0.0f;
  int cbits = 0;  // wave-uniform accumulated exponent

  const float* embase = em + (size_t)b * SLEN * NT;

  auto dostep = [&](float ee) {
    // s_j = sum_i q_i * E[i][j]; q_i broadcast via readlane -> SGPR fma operand
    float s0 = 0.f, s1 = 0.f, s2 = 0.f, s3 = 0.f;
#pragma unroll
    for (int i = 0; i < NT; i += 4) {
      s0 = fmaf(bcast(q, i + 0), Ec[i + 0], s0);
      s1 = fmaf(bcast(q, i + 1), Ec[i + 1], s1);
      s2 = fmaf(bcast(q, i + 2), Ec[i + 2], s2);
      s3 = fmaf(bcast(q, i + 3), Ec[i + 3], s3);
    }
    q = ((s0 + s1) + (s2 + s3)) * __expf(ee);  // __expf(ee) independent of chain
  };

  auto renorm = [&]() {
    // shared power-of-2 rescale; probes are uniform -> cbits stays uniform
    float mx = fmaxf(fmaxf(bcast(q, 5), bcast(q, 21)),
                     fmaxf(bcast(q, 37), 1e-30f));
    int ex;
    (void)frexpf(mx, &ex);
    q = ldexpf(q, -ex);
    cbits += ex;
  };

  for (int c0 = 0; c0 < len; c0 += 64) {
    const float* src = embase + (size_t)c0 * NT;
#pragma unroll
    for (int k = 0; k < 12; ++k)
      gload16(src + k * 256 + lane * 4, lem + k * 256);
    asm volatile("s_waitcnt vmcnt(0)" ::: "memory");

    const int tend = (len - c0 < 64) ? (len - c0) : 64;
    int tt = 0;
    for (; tt + 4 <= tend; tt += 4) {
      // 4 independent ds_reads issued up-front; latency hides under step 0
      float e0 = lem[(tt + 0) * NT + lane];
      float e1 = lem[(tt + 1) * NT + lane];
      float e2 = lem[(tt + 2) * NT + lane];
      float e3 = lem[(tt + 3) * NT + lane];
      dostep(e0);
      dostep(e1);
      dostep(e2);
      dostep(e3);
      renorm();
    }
    for (; tt < tend; ++tt) dostep(lem[tt * NT + lane]);
    renorm();
  }

  // logZ = cbits*ln2 + LSE_j(log q_j + T[STOP][j])   (once; shuffles OK here)
  float lq = (q > 0.f) ? __logf(q) : -__builtin_inff();
  float term =
      (lane < NT) ? lq + Tr[TAG_STOP * NT + lane] : -__builtin_inff();
  float m2 = term;
#pragma unroll
  for (int d = 32; d >= 1; d >>= 1) m2 = fmaxf(m2, __shfl_xor(m2, d));
  float ex = (lane < NT) ? __expf(term - m2) : 0.0f;
#pragma unroll
  for (int d = 32; d >= 1; d >>= 1) ex += __shfl_xor(ex, d);
  const float logZ = m2 + __logf(ex) + (float)cbits * 0.69314718055994531f;

  // gold score (unchanged from R2: matched at absmax 0)
  const int* trow = tags + (size_t)b * SLEN;
  float g = 0.f;
  for (int t = lane; t < len; t += 64) {
    const int tag = trow[t];
    const int prev = (t == 0) ? TAG_START : trow[t - 1];
    g += Tr[tag * NT + prev] + embase[(size_t)t * NT + tag];
  }
#pragma unroll
  for (int d = 32; d >= 1; d >>= 1) g += __shfl_xor(g, d);

  if (lane == 0) {
    const int last = trow[len - 1];
    ws[b] = logZ - (g + Tr[TAG_STOP * NT + last]);
  }
}

// Deterministic tree-mean over B per-batch values (no atomics).
__global__ void crf_reduce_kernel(const float* __restrict__ ws,
                                  float* __restrict__ out, int n) {
  const int tid = threadIdx.x;
  float v = (tid < n) ? ws[tid] : 0.f;
#pragma unroll
  for (int d = 32; d >= 1; d >>= 1) v += __shfl_xor(v, d);
  __shared__ float part[16];
  if ((tid & 63) == 0) part[tid >> 6] = v;
  __syncthreads();
  if (tid == 0) {
    float s = 0.f;
    for (int i = 0; i < 16; ++i) s += part[i];
    out[0] = s / (float)n;
  }
}

extern "C" void kernel_launch(void* const* d_in, const int* in_sizes, int n_in,
                              void* d_out, int out_size, void* d_ws, size_t ws_size,
                              hipStream_t stream) {
  const float* em = (const float*)d_in[0];
  const int* tags = (const int*)d_in[1];
  const int* mask = (const int*)d_in[2];
  const float* Tr = (const float*)d_in[3];
  const int B = in_sizes[0] / (SLEN * NT);  // 1024

  float* ws = (float*)d_ws;  // B floats
  crf_fwd_kernel<<<B, 64, 0, stream>>>(em, tags, mask, Tr, ws);
  crf_reduce_kernel<<<1, 1024, 0, stream>>>(ws, (float*)d_out, B);
}